// Round 12
// baseline (347.124 us; speedup 1.0000x reference)
//
#include <hip/hip_runtime.h>
#include <hip/hip_fp16.h>

typedef _Float16 f16;
typedef _Float16 f16x8 __attribute__((ext_vector_type(8)));
typedef float f32x4 __attribute__((ext_vector_type(4)));

constexpr int C = 128;     // channels
constexpr int V = 65536;   // voxels
constexpr int PTS = 64;    // points per MFMA tile
constexpr int BLOCK = 256; // 4 waves
constexpr int BKT = 64;    // bucket capacity per voxel (P(overflow) ~ 1e-26)

union U16 { uint4 u; f16x8 h; };

// -------------------------------------------------------------------------
// Kernel 0: zero the counters (rocclr's small fill kernel is latency-bound).
// -------------------------------------------------------------------------
__global__ void zero_cnt(int4* __restrict__ cnt) {
    const int t = blockIdx.x * blockDim.x + threadIdx.x;
    cnt[t] = make_int4(0, 0, 0, 0);
}

// -------------------------------------------------------------------------
// Kernel 1: bucket scatter — fixed-stride CSR, no scan needed.
// -------------------------------------------------------------------------
__global__ void bucket_scatter(const int* __restrict__ idx, int* __restrict__ cnt,
                               int* __restrict__ bucket, int n) {
    const int t = blockIdx.x * blockDim.x + threadIdx.x;
    if (t < n) {
        const int v = idx[t];
        const int slot = atomicAdd(&cnt[v], 1);
        if (slot < BKT) bucket[(v << 6) + slot] = t;
    }
}

// -------------------------------------------------------------------------
// Kernel 2: pooling — one wave per voxel, fp32 accumulate (4-deep ILP),
// f16 mean store.
// -------------------------------------------------------------------------
__global__ void __launch_bounds__(256)
pool_bucket(const float* __restrict__ feats, const int* __restrict__ bucket,
            const int* __restrict__ cnt, __half* __restrict__ pooled) {
    const int v = blockIdx.x * 4 + (threadIdx.x >> 6);
    const int lane = threadIdx.x & 63;
    const int e = min(cnt[v], BKT);
    const int* b = bucket + (v << 6);
    float ax = 0.f, ay = 0.f, bx = 0.f, by = 0.f;
    float cx = 0.f, cy = 0.f, dx = 0.f, dy = 0.f;
    int j = 0;
    for (; j + 4 <= e; j += 4) {
        const int p0 = b[j], p1 = b[j + 1], p2 = b[j + 2], p3 = b[j + 3];
        const float2 f0 = *reinterpret_cast<const float2*>(feats + (size_t)p0 * C + lane * 2);
        const float2 f1 = *reinterpret_cast<const float2*>(feats + (size_t)p1 * C + lane * 2);
        const float2 f2 = *reinterpret_cast<const float2*>(feats + (size_t)p2 * C + lane * 2);
        const float2 f3 = *reinterpret_cast<const float2*>(feats + (size_t)p3 * C + lane * 2);
        ax += f0.x; ay += f0.y; bx += f1.x; by += f1.y;
        cx += f2.x; cy += f2.y; dx += f3.x; dy += f3.y;
    }
    for (; j < e; ++j) {
        const int p0 = b[j];
        const float2 f0 = *reinterpret_cast<const float2*>(feats + (size_t)p0 * C + lane * 2);
        ax += f0.x; ay += f0.y;
    }
    const float rc = e ? 1.0f / (float)e : 0.f;
    *reinterpret_cast<__half2*>(pooled + (size_t)v * C + lane * 2) =
        __floats2half2_rn((ax + bx + cx + dx) * rc, (ay + by + cy + dy) * rc);
}

// -------------------------------------------------------------------------
// Kernel 3: fused gather + 2-layer MLP via f16 MFMA (16x16x32).
//   os  = feats - pooled_mean[idx]   (staged in 16 KB LDS, f16, swizzled)
//   h   = relu(os @ W1 + b1) * f     (f RE-READ from global: rows are L2-hot
//                                     from staging; kills the 16 KB f_lds)
//   out = relu(h @ W2 + b2)
// LDS = 16 KB total; staging in 2 halves to cap transient VGPRs.
// Goal: VGPR <= ~120 AND LDS 16 KB -> 4 blocks/CU (16 waves) -- 2x the TLP
// of all previous variants (R9/R11 stuck at ~8 waves, issue-bound).
// -------------------------------------------------------------------------
__global__ void __launch_bounds__(BLOCK)
mlp_mfma(const float* __restrict__ feats,
         const float* __restrict__ W1g,
         const float* __restrict__ b1g,
         const float* __restrict__ W2g,
         const float* __restrict__ b2g,
         const int* __restrict__ idx,
         const __half* __restrict__ pooled,
         float* __restrict__ out,
         int n) {
    __shared__ f16 osh_lds[PTS * C];  // 16 KB: holds os, then h (XOR-swizzled)

    const int t = threadIdx.x;
    const int lane = t & 63;
    const int wv = t >> 6;
    const int l15 = lane & 15;
    const int lg = lane >> 4;
    const int chBase = 32 * wv;

    // Weight fragments in registers (B-frag: col = lane&15, k = (lane>>4)*8+j)
    const int ch0 = chBase + l15;
    const int ch1 = chBase + 16 + l15;
    f16x8 w1f[2][4], w2f[2][4];
#pragma unroll
    for (int m = 0; m < 2; ++m) {
        const int ch = (m == 0) ? ch0 : ch1;
#pragma unroll
        for (int s = 0; s < 4; ++s) {
            f16x8 a, b;
#pragma unroll
            for (int j = 0; j < 8; ++j) {
                const int k = s * 32 + lg * 8 + j;
                a[j] = (f16)W1g[k * C + ch];
                b[j] = (f16)W2g[k * C + ch];
            }
            w1f[m][s] = a;
            w2f[m][s] = b;
        }
    }
    const float b1v[2] = {b1g[ch0], b1g[ch1]};
    const float b2v[2] = {b2g[ch0], b2g[ch1]};

    const int sp = t >> 2;          // point slot 0..63
    const int sc = (t & 3) * 32;    // channel base 0/32/64/96

    for (long long base = (long long)blockIdx.x * PTS; base < n;
         base += (long long)gridDim.x * PTS) {
        // ---- Stage os = f - mean into LDS (two 16-ch halves, low reg peak)
        {
            const long long p = base + sp;
            const bool valid = p < n;
            const int v = valid ? idx[p] : 0;
#pragma unroll
            for (int half = 0; half < 2; ++half) {
                const int c0 = sc + half * 16;
                union { float4 v4[4]; float f[16]; } ff;
                union { uint4 u[2]; __half h[16]; } pl;
                if (valid) {
#pragma unroll
                    for (int j = 0; j < 4; ++j)
                        ff.v4[j] = *reinterpret_cast<const float4*>(feats + (size_t)p * C + c0 + j * 4);
                    const uint4* pp = reinterpret_cast<const uint4*>(pooled + (size_t)v * C + c0);
#pragma unroll
                    for (int j = 0; j < 2; ++j) pl.u[j] = pp[j];
                } else {
#pragma unroll
                    for (int j = 0; j < 4; ++j) ff.v4[j] = make_float4(0.f, 0.f, 0.f, 0.f);
#pragma unroll
                    for (int j = 0; j < 2; ++j) pl.u[j] = make_uint4(0, 0, 0, 0);
                }
                union { uint4 u[2]; f16 h[16]; } osv;
#pragma unroll
                for (int j = 0; j < 16; ++j)
                    osv.h[j] = (f16)(ff.f[j] - __half2float(pl.h[j]));
#pragma unroll
                for (int u = 0; u < 2; ++u) {
                    const int byte = (sp * 256 + (c0 + u * 8) * 2) ^ ((sp & 7) << 4);
                    *reinterpret_cast<uint4*>(reinterpret_cast<char*>(osh_lds) + byte) = osv.u[u];
                }
            }
        }
        __syncthreads();  // bar1: os staged

        // ---- Layer 1: acc = os @ W1 + b1 --------------------------------
        f32x4 acc[2][4];
#pragma unroll
        for (int m = 0; m < 2; ++m)
#pragma unroll
            for (int q = 0; q < 4; ++q)
                acc[m][q] = (f32x4){b1v[m], b1v[m], b1v[m], b1v[m]};

#pragma unroll
        for (int s = 0; s < 4; ++s) {
            f16x8 af[4];
#pragma unroll
            for (int q = 0; q < 4; ++q) {
                const int p = q * 16 + l15;
                const int byte = (p * 256 + (s * 32 + lg * 8) * 2) ^ ((p & 7) << 4);
                U16 tmp;
                tmp.u = *reinterpret_cast<const uint4*>(reinterpret_cast<const char*>(osh_lds) + byte);
                af[q] = tmp.h;
            }
#pragma unroll
            for (int m = 0; m < 2; ++m)
#pragma unroll
                for (int q = 0; q < 4; ++q)
                    acc[m][q] = __builtin_amdgcn_mfma_f32_16x16x32_f16(af[q], w1f[m][s], acc[m][q], 0, 0, 0);
        }
        __syncthreads();  // bar2: all os reads done -> safe to overwrite with h

        // ---- h = relu(acc) * f -> osh_lds; f re-read from global (L2-hot)
        // C/D layout: col = lane&15 (channel), row = (lane>>4)*4 + reg (point)
#pragma unroll
        for (int m = 0; m < 2; ++m) {
            const int ch = chBase + m * 16 + l15;
#pragma unroll
            for (int q = 0; q < 4; ++q)
#pragma unroll
                for (int r = 0; r < 4; ++r) {
                    const int d = q * 16 + lg * 4 + r;
                    const long long gp = base + d;
                    const float fval = (gp < n) ? feats[gp * C + ch] : 0.f;
                    const int byte = (d * 256 + ch * 2) ^ ((d & 7) << 4);
                    const float hv = fmaxf(acc[m][q][r], 0.f) * fval;
                    *reinterpret_cast<f16*>(reinterpret_cast<char*>(osh_lds) + byte) = (f16)hv;
                }
        }
        __syncthreads();  // bar3: h ready

        // ---- Layer 2: out = relu(h @ W2 + b2) ---------------------------
        f32x4 acc2[2][4];
#pragma unroll
        for (int m = 0; m < 2; ++m)
#pragma unroll
            for (int q = 0; q < 4; ++q)
                acc2[m][q] = (f32x4){b2v[m], b2v[m], b2v[m], b2v[m]};

#pragma unroll
        for (int s = 0; s < 4; ++s) {
            f16x8 af[4];
#pragma unroll
            for (int q = 0; q < 4; ++q) {
                const int p = q * 16 + l15;
                const int byte = (p * 256 + (s * 32 + lg * 8) * 2) ^ ((p & 7) << 4);
                U16 tmp;
                tmp.u = *reinterpret_cast<const uint4*>(reinterpret_cast<const char*>(osh_lds) + byte);
                af[q] = tmp.h;
            }
#pragma unroll
            for (int m = 0; m < 2; ++m)
#pragma unroll
                for (int q = 0; q < 4; ++q)
                    acc2[m][q] = __builtin_amdgcn_mfma_f32_16x16x32_f16(af[q], w2f[m][s], acc2[m][q], 0, 0, 0);
        }

#pragma unroll
        for (int m = 0; m < 2; ++m) {
            const int ch = chBase + m * 16 + l15;
#pragma unroll
            for (int q = 0; q < 4; ++q)
#pragma unroll
                for (int r = 0; r < 4; ++r) {
                    const int d = q * 16 + lg * 4 + r;
                    const long long gp = base + d;
                    if (gp < n)
                        out[gp * C + ch] = fmaxf(acc2[m][q][r], 0.f);
                }
        }
        __syncthreads();  // bar4: h reads done before next-iter staging
    }
}

// -------------------------------------------------------------------------
// Launch
// -------------------------------------------------------------------------
extern "C" void kernel_launch(void* const* d_in, const int* in_sizes, int n_in,
                              void* d_out, int out_size, void* d_ws, size_t ws_size,
                              hipStream_t stream) {
    const float* feats = (const float*)d_in[0];
    const float* W1    = (const float*)d_in[1];
    const float* b1    = (const float*)d_in[2];
    const float* W2    = (const float*)d_in[3];
    const float* b2    = (const float*)d_in[4];
    const int*   idx   = (const int*)d_in[5];
    float*       out   = (float*)d_out;

    const int n = in_sizes[5];

    // Workspace: cnt[V] int | bucket[V*64] int | pooled[V*C] f16
    int* cnt    = (int*)d_ws;
    int* bucket = cnt + V;
    __half* pooled = (__half*)(bucket + (size_t)V * BKT);

    zero_cnt<<<V / (256 * 4), 256, 0, stream>>>((int4*)cnt);
    bucket_scatter<<<(n + 255) / 256, 256, 0, stream>>>(idx, cnt, bucket, n);
    pool_bucket<<<V / 4, 256, 0, stream>>>(feats, bucket, cnt, pooled);
    mlp_mfma<<<1024, BLOCK, 0, stream>>>(feats, W1, b1, W2, b2, idx,
                                         pooled, out, n);
}

// Round 13
// 206.976 us; speedup vs baseline: 1.6771x; 1.6771x over previous
//
#include <hip/hip_runtime.h>
#include <hip/hip_fp16.h>

typedef _Float16 f16;
typedef _Float16 f16x8 __attribute__((ext_vector_type(8)));
typedef float f32x4 __attribute__((ext_vector_type(4)));

constexpr int C = 128;        // channels
constexpr int V = 65536;      // voxels
constexpr int PTS = 64;       // points per MFMA tile
constexpr int MLP_BLOCK = 512;// 8 waves; each wave owns 16 output channels
constexpr int BKT = 64;       // bucket capacity per voxel (P(overflow) ~ 1e-26)

union U16 { uint4 u; f16x8 h; };

// -------------------------------------------------------------------------
// Kernel 0: zero the counters (rocclr's small fill kernel is latency-bound).
// -------------------------------------------------------------------------
__global__ void zero_cnt(int4* __restrict__ cnt) {
    const int t = blockIdx.x * blockDim.x + threadIdx.x;
    cnt[t] = make_int4(0, 0, 0, 0);
}

// -------------------------------------------------------------------------
// Kernel 1: bucket scatter — fixed-stride CSR, no scan needed.
// -------------------------------------------------------------------------
__global__ void bucket_scatter(const int* __restrict__ idx, int* __restrict__ cnt,
                               int* __restrict__ bucket, int n) {
    const int t = blockIdx.x * blockDim.x + threadIdx.x;
    if (t < n) {
        const int v = idx[t];
        const int slot = atomicAdd(&cnt[v], 1);
        if (slot < BKT) bucket[(v << 6) + slot] = t;
    }
}

// -------------------------------------------------------------------------
// Kernel 2: pooling — one wave per voxel, fp32 accumulate (4-deep ILP),
// f16 mean store.
// -------------------------------------------------------------------------
__global__ void __launch_bounds__(256)
pool_bucket(const float* __restrict__ feats, const int* __restrict__ bucket,
            const int* __restrict__ cnt, __half* __restrict__ pooled) {
    const int v = blockIdx.x * 4 + (threadIdx.x >> 6);
    const int lane = threadIdx.x & 63;
    const int e = min(cnt[v], BKT);
    const int* b = bucket + (v << 6);
    float ax = 0.f, ay = 0.f, bx = 0.f, by = 0.f;
    float cx = 0.f, cy = 0.f, dx = 0.f, dy = 0.f;
    int j = 0;
    for (; j + 4 <= e; j += 4) {
        const int p0 = b[j], p1 = b[j + 1], p2 = b[j + 2], p3 = b[j + 3];
        const float2 f0 = *reinterpret_cast<const float2*>(feats + (size_t)p0 * C + lane * 2);
        const float2 f1 = *reinterpret_cast<const float2*>(feats + (size_t)p1 * C + lane * 2);
        const float2 f2 = *reinterpret_cast<const float2*>(feats + (size_t)p2 * C + lane * 2);
        const float2 f3 = *reinterpret_cast<const float2*>(feats + (size_t)p3 * C + lane * 2);
        ax += f0.x; ay += f0.y; bx += f1.x; by += f1.y;
        cx += f2.x; cy += f2.y; dx += f3.x; dy += f3.y;
    }
    for (; j < e; ++j) {
        const int p0 = b[j];
        const float2 f0 = *reinterpret_cast<const float2*>(feats + (size_t)p0 * C + lane * 2);
        ax += f0.x; ay += f0.y;
    }
    const float rc = e ? 1.0f / (float)e : 0.f;
    *reinterpret_cast<__half2*>(pooled + (size_t)v * C + lane * 2) =
        __floats2half2_rn((ax + bx + cx + dx) * rc, (ay + by + cy + dy) * rc);
}

// -------------------------------------------------------------------------
// Kernel 3: fused gather + 2-layer MLP via f16 MFMA (16x16x32).
// 8 waves x 16 output channels each (halves weight regs 64 -> 32: every
// previous 4-wave/32-ch variant sat at VGPR 108-136, the 128 cliff).
//   os  = feats - pooled_mean[idx]   (os_lds, f16, XOR-swizzled)
//   h   = relu(os @ W1 + b1) * f     (f from f_lds; h -> h_lds)
//   out = relu(h @ W2 + b2)
// 2 barriers/tile: separate os/f/h buffers make bar-after-L1 and
// bar-after-store provably redundant (stage(i+1) races only with L2's
// h_lds reads -- different buffer; bar1(i+1) orders h-write(i+1)).
// -------------------------------------------------------------------------
__global__ void __launch_bounds__(MLP_BLOCK)
mlp_mfma(const float* __restrict__ feats,
         const float* __restrict__ W1g,
         const float* __restrict__ b1g,
         const float* __restrict__ W2g,
         const float* __restrict__ b2g,
         const int* __restrict__ idx,
         const __half* __restrict__ pooled,
         float* __restrict__ out,
         int n) {
    __shared__ f16 os_lds[PTS * C];  // 16 KB, XOR-swizzled rows
    __shared__ f16 f_lds[PTS * C];   // 16 KB
    __shared__ f16 h_lds[PTS * C];   // 16 KB

    const int t = threadIdx.x;
    const int lane = t & 63;
    const int wv = t >> 6;           // wave 0..7
    const int l15 = lane & 15;
    const int lg = lane >> 4;        // 0..3
    const int ch = 16 * wv + l15;    // this lane's output channel (16/wave)

    // Weight fragments: ONE 16-ch slice per wave, both layers = 32 VGPRs.
    // B-frag: col = lane&15, k = (lane>>4)*8 + j.
    f16x8 w1f[4], w2f[4];
#pragma unroll
    for (int s = 0; s < 4; ++s) {
        f16x8 a, b;
#pragma unroll
        for (int j = 0; j < 8; ++j) {
            const int k = s * 32 + lg * 8 + j;
            a[j] = (f16)W1g[k * C + ch];
            b[j] = (f16)W2g[k * C + ch];
        }
        w1f[s] = a;
        w2f[s] = b;
    }
    const float b1v = b1g[ch];
    const float b2v = b2g[ch];

    // Staging: thread covers point sp, channels sc..sc+15 (8 threads/point).
    const int sp = t >> 3;
    const int sc = (t & 7) * 16;

    for (long long base = (long long)blockIdx.x * PTS; base < n;
         base += (long long)gridDim.x * PTS) {
        // ---- Stage os (= f - mean) and f into LDS as f16, swizzled ------
        {
            const long long p = base + sp;
            union { float4 v4[4]; float f[16]; } ff;
            union { uint4 u[2]; __half h[16]; } pl;
            if (p < n) {
#pragma unroll
                for (int j = 0; j < 4; ++j)
                    ff.v4[j] = *reinterpret_cast<const float4*>(feats + (size_t)p * C + sc + j * 4);
                const int v = idx[p];
                const uint4* pp = reinterpret_cast<const uint4*>(pooled + (size_t)v * C + sc);
#pragma unroll
                for (int j = 0; j < 2; ++j) pl.u[j] = pp[j];
            } else {
#pragma unroll
                for (int j = 0; j < 4; ++j) ff.v4[j] = make_float4(0.f, 0.f, 0.f, 0.f);
#pragma unroll
                for (int j = 0; j < 2; ++j) pl.u[j] = make_uint4(0, 0, 0, 0);
            }
            union { uint4 u[2]; f16 h[16]; } osv, fvh;
#pragma unroll
            for (int j = 0; j < 16; ++j) {
                const float fj = ff.f[j];
                osv.h[j] = (f16)(fj - __half2float(pl.h[j]));
                fvh.h[j] = (f16)fj;
            }
#pragma unroll
            for (int u = 0; u < 2; ++u) {
                const int byte = (sp * 256 + (sc + u * 8) * 2) ^ ((sp & 7) << 4);
                *reinterpret_cast<uint4*>(reinterpret_cast<char*>(os_lds) + byte) = osv.u[u];
                *reinterpret_cast<uint4*>(reinterpret_cast<char*>(f_lds) + byte) = fvh.u[u];
            }
        }
        __syncthreads();  // bar1: os/f staged (also orders h-write vs prior L2)

        // ---- Layer 1: acc = os @ W1 + b1 (16 MFMA/wave) ------------------
        f32x4 acc[4];
#pragma unroll
        for (int q = 0; q < 4; ++q)
            acc[q] = (f32x4){b1v, b1v, b1v, b1v};

#pragma unroll
        for (int s = 0; s < 4; ++s) {
            f16x8 af[4];
#pragma unroll
            for (int q = 0; q < 4; ++q) {
                const int p = q * 16 + l15;
                const int byte = (p * 256 + (s * 32 + lg * 8) * 2) ^ ((p & 7) << 4);
                U16 tmp;
                tmp.u = *reinterpret_cast<const uint4*>(reinterpret_cast<const char*>(os_lds) + byte);
                af[q] = tmp.h;
            }
#pragma unroll
            for (int q = 0; q < 4; ++q)
                acc[q] = __builtin_amdgcn_mfma_f32_16x16x32_f16(af[q], w1f[s], acc[q], 0, 0, 0);
        }

        // ---- h = relu(acc) * f -> h_lds (own 16-ch slice, all 64 pts) ----
        // C/D layout: col = lane&15 (channel), row = (lane>>4)*4 + reg (point)
#pragma unroll
        for (int q = 0; q < 4; ++q)
#pragma unroll
            for (int r = 0; r < 4; ++r) {
                const int d = q * 16 + lg * 4 + r;
                const int byte = (d * 256 + ch * 2) ^ ((d & 7) << 4);
                const float fval = (float)*reinterpret_cast<const f16*>(
                    reinterpret_cast<const char*>(f_lds) + byte);
                const float hv = fmaxf(acc[q][r], 0.f) * fval;
                *reinterpret_cast<f16*>(reinterpret_cast<char*>(h_lds) + byte) = (f16)hv;
            }
        __syncthreads();  // bar2: h complete (and all os/f reads done)

        // ---- Layer 2: out = relu(h @ W2 + b2) ----------------------------
        f32x4 acc2[4];
#pragma unroll
        for (int q = 0; q < 4; ++q)
            acc2[q] = (f32x4){b2v, b2v, b2v, b2v};

#pragma unroll
        for (int s = 0; s < 4; ++s) {
            f16x8 af[4];
#pragma unroll
            for (int q = 0; q < 4; ++q) {
                const int p = q * 16 + l15;
                const int byte = (p * 256 + (s * 32 + lg * 8) * 2) ^ ((p & 7) << 4);
                U16 tmp;
                tmp.u = *reinterpret_cast<const uint4*>(reinterpret_cast<const char*>(h_lds) + byte);
                af[q] = tmp.h;
            }
#pragma unroll
            for (int q = 0; q < 4; ++q)
                acc2[q] = __builtin_amdgcn_mfma_f32_16x16x32_f16(af[q], w2f[s], acc2[q], 0, 0, 0);
        }

#pragma unroll
        for (int q = 0; q < 4; ++q)
#pragma unroll
            for (int r = 0; r < 4; ++r) {
                const int d = q * 16 + lg * 4 + r;
                const long long gp = base + d;
                if (gp < n)
                    out[gp * C + ch] = fmaxf(acc2[q][r], 0.f);
            }
        // No 3rd barrier: next stage writes os/f only; the live h_lds reads
        // belong to threads that must pass bar1(i+1) before h is rewritten.
    }
}

// -------------------------------------------------------------------------
// Launch
// -------------------------------------------------------------------------
extern "C" void kernel_launch(void* const* d_in, const int* in_sizes, int n_in,
                              void* d_out, int out_size, void* d_ws, size_t ws_size,
                              hipStream_t stream) {
    const float* feats = (const float*)d_in[0];
    const float* W1    = (const float*)d_in[1];
    const float* b1    = (const float*)d_in[2];
    const float* W2    = (const float*)d_in[3];
    const float* b2    = (const float*)d_in[4];
    const int*   idx   = (const int*)d_in[5];
    float*       out   = (float*)d_out;

    const int n = in_sizes[5];

    // Workspace: cnt[V] int | bucket[V*64] int | pooled[V*C] f16
    int* cnt    = (int*)d_ws;
    int* bucket = cnt + V;
    __half* pooled = (__half*)(bucket + (size_t)V * BKT);

    zero_cnt<<<V / (256 * 4), 256, 0, stream>>>((int4*)cnt);
    bucket_scatter<<<(n + 255) / 256, 256, 0, stream>>>(idx, cnt, bucket, n);
    pool_bucket<<<V / 4, 256, 0, stream>>>(feats, bucket, cnt, pooled);
    mlp_mfma<<<512, MLP_BLOCK, 0, stream>>>(feats, W1, b1, W2, b2, idx,
                                            pooled, out, n);
}

// Round 14
// 203.359 us; speedup vs baseline: 1.7070x; 1.0178x over previous
//
#include <hip/hip_runtime.h>
#include <hip/hip_fp16.h>

typedef _Float16 f16;
typedef _Float16 f16x8 __attribute__((ext_vector_type(8)));
typedef float f32x4 __attribute__((ext_vector_type(4)));

constexpr int C = 128;        // channels
constexpr int V = 65536;      // voxels
constexpr int PTS = 64;       // points per MFMA tile
constexpr int MLP_BLOCK = 512;// 8 waves; each wave owns 16 output channels
constexpr int BKT = 64;       // bucket capacity per voxel (P(overflow) ~ 1e-26)

union U16 { uint4 u; f16x8 h; };

// -------------------------------------------------------------------------
// Kernel 0: zero the counters (rocclr's small fill kernel is latency-bound).
// -------------------------------------------------------------------------
__global__ void zero_cnt(int4* __restrict__ cnt) {
    const int t = blockIdx.x * blockDim.x + threadIdx.x;
    cnt[t] = make_int4(0, 0, 0, 0);
}

// -------------------------------------------------------------------------
// Kernel 1: bucket scatter — fixed-stride CSR, no scan needed.
// -------------------------------------------------------------------------
__global__ void bucket_scatter(const int* __restrict__ idx, int* __restrict__ cnt,
                               int* __restrict__ bucket, int n) {
    const int t = blockIdx.x * blockDim.x + threadIdx.x;
    if (t < n) {
        const int v = idx[t];
        const int slot = atomicAdd(&cnt[v], 1);
        if (slot < BKT) bucket[(v << 6) + slot] = t;
    }
}

// -------------------------------------------------------------------------
// Kernel 2: pooling — one wave per voxel; HALF-WAVE per point row with
// float4 loads (32 lanes x 16B = 512B row), 2-deep unroll -> 4 rows in
// flight per wave (2x the bytes-in-flight of the R13 float2 version).
// Cross-half combine via shfl_xor(32); f16 mean store from lanes 0-31.
// -------------------------------------------------------------------------
__global__ void __launch_bounds__(256)
pool_bucket(const float* __restrict__ feats, const int* __restrict__ bucket,
            const int* __restrict__ cnt, __half* __restrict__ pooled) {
    const int v = blockIdx.x * 4 + (threadIdx.x >> 6);
    const int lane = threadIdx.x & 63;
    const int half = lane >> 5;      // 0 or 1: which point of a pair
    const int l32 = lane & 31;       // channel quad: channels l32*4..+3
    const int e = min(cnt[v], BKT);
    const int* b = bucket + (v << 6);

    f32x4 a0 = {0.f, 0.f, 0.f, 0.f};
    f32x4 a1 = {0.f, 0.f, 0.f, 0.f};
    int j = half;
    for (; j + 2 < e; j += 4) {      // handles rows j and j+2 per iter
        const int p0 = b[j];
        const int p1 = b[j + 2];
        a0 += *reinterpret_cast<const f32x4*>(feats + (size_t)p0 * C + l32 * 4);
        a1 += *reinterpret_cast<const f32x4*>(feats + (size_t)p1 * C + l32 * 4);
    }
    if (j < e) {
        const int p0 = b[j];
        a0 += *reinterpret_cast<const f32x4*>(feats + (size_t)p0 * C + l32 * 4);
    }
    a0 += a1;
    // combine the two halves (channels match: same l32)
#pragma unroll
    for (int c = 0; c < 4; ++c)
        a0[c] += __shfl_xor(a0[c], 32);

    if (half == 0) {
        const float rc = e ? 1.0f / (float)e : 0.f;
        const __half2 lo = __floats2half2_rn(a0[0] * rc, a0[1] * rc);
        const __half2 hi = __floats2half2_rn(a0[2] * rc, a0[3] * rc);
        union { uint2 u; __half2 h[2]; } pk;
        pk.h[0] = lo; pk.h[1] = hi;
        *reinterpret_cast<uint2*>(pooled + (size_t)v * C + l32 * 4) = pk.u;
    }
}

// -------------------------------------------------------------------------
// Kernel 3: fused gather + 2-layer MLP via f16 MFMA (16x16x32).
// 8 waves x 16 output channels each (R13 structure — broke the 128-VGPR
// wall: weight regs 64 -> 32).
//   os  = feats - pooled_mean[idx]   (os_lds, f16, XOR-swizzled)
//   h   = relu(os @ W1 + b1) * f     (f from f_lds; h -> h_lds)
//   out = relu(h @ W2 + b2)
// 2 barriers/tile (separate os/f/h buffers make the others redundant).
// -------------------------------------------------------------------------
__global__ void __launch_bounds__(MLP_BLOCK)
mlp_mfma(const float* __restrict__ feats,
         const float* __restrict__ W1g,
         const float* __restrict__ b1g,
         const float* __restrict__ W2g,
         const float* __restrict__ b2g,
         const int* __restrict__ idx,
         const __half* __restrict__ pooled,
         float* __restrict__ out,
         int n) {
    __shared__ f16 os_lds[PTS * C];  // 16 KB, XOR-swizzled rows
    __shared__ f16 f_lds[PTS * C];   // 16 KB
    __shared__ f16 h_lds[PTS * C];   // 16 KB

    const int t = threadIdx.x;
    const int lane = t & 63;
    const int wv = t >> 6;           // wave 0..7
    const int l15 = lane & 15;
    const int lg = lane >> 4;        // 0..3
    const int ch = 16 * wv + l15;    // this lane's output channel (16/wave)

    // Weight fragments: ONE 16-ch slice per wave, both layers = 32 VGPRs.
    // B-frag: col = lane&15, k = (lane>>4)*8 + j.
    f16x8 w1f[4], w2f[4];
#pragma unroll
    for (int s = 0; s < 4; ++s) {
        f16x8 a, b;
#pragma unroll
        for (int j = 0; j < 8; ++j) {
            const int k = s * 32 + lg * 8 + j;
            a[j] = (f16)W1g[k * C + ch];
            b[j] = (f16)W2g[k * C + ch];
        }
        w1f[s] = a;
        w2f[s] = b;
    }
    const float b1v = b1g[ch];
    const float b2v = b2g[ch];

    // Staging: thread covers point sp, channels sc..sc+15 (8 threads/point).
    const int sp = t >> 3;
    const int sc = (t & 7) * 16;

    for (long long base = (long long)blockIdx.x * PTS; base < n;
         base += (long long)gridDim.x * PTS) {
        // ---- Stage os (= f - mean) and f into LDS as f16, swizzled ------
        {
            const long long p = base + sp;
            union { float4 v4[4]; float f[16]; } ff;
            union { uint4 u[2]; __half h[16]; } pl;
            if (p < n) {
#pragma unroll
                for (int j = 0; j < 4; ++j)
                    ff.v4[j] = *reinterpret_cast<const float4*>(feats + (size_t)p * C + sc + j * 4);
                const int v = idx[p];
                const uint4* pp = reinterpret_cast<const uint4*>(pooled + (size_t)v * C + sc);
#pragma unroll
                for (int j = 0; j < 2; ++j) pl.u[j] = pp[j];
            } else {
#pragma unroll
                for (int j = 0; j < 4; ++j) ff.v4[j] = make_float4(0.f, 0.f, 0.f, 0.f);
#pragma unroll
                for (int j = 0; j < 2; ++j) pl.u[j] = make_uint4(0, 0, 0, 0);
            }
            union { uint4 u[2]; f16 h[16]; } osv, fvh;
#pragma unroll
            for (int j = 0; j < 16; ++j) {
                const float fj = ff.f[j];
                osv.h[j] = (f16)(fj - __half2float(pl.h[j]));
                fvh.h[j] = (f16)fj;
            }
#pragma unroll
            for (int u = 0; u < 2; ++u) {
                const int byte = (sp * 256 + (sc + u * 8) * 2) ^ ((sp & 7) << 4);
                *reinterpret_cast<uint4*>(reinterpret_cast<char*>(os_lds) + byte) = osv.u[u];
                *reinterpret_cast<uint4*>(reinterpret_cast<char*>(f_lds) + byte) = fvh.u[u];
            }
        }
        __syncthreads();  // bar1: os/f staged (also orders h-write vs prior L2)

        // ---- Layer 1: acc = os @ W1 + b1 (16 MFMA/wave) ------------------
        f32x4 acc[4];
#pragma unroll
        for (int q = 0; q < 4; ++q)
            acc[q] = (f32x4){b1v, b1v, b1v, b1v};

#pragma unroll
        for (int s = 0; s < 4; ++s) {
            f16x8 af[4];
#pragma unroll
            for (int q = 0; q < 4; ++q) {
                const int p = q * 16 + l15;
                const int byte = (p * 256 + (s * 32 + lg * 8) * 2) ^ ((p & 7) << 4);
                U16 tmp;
                tmp.u = *reinterpret_cast<const uint4*>(reinterpret_cast<const char*>(os_lds) + byte);
                af[q] = tmp.h;
            }
#pragma unroll
            for (int q = 0; q < 4; ++q)
                acc[q] = __builtin_amdgcn_mfma_f32_16x16x32_f16(af[q], w1f[s], acc[q], 0, 0, 0);
        }

        // ---- h = relu(acc) * f -> h_lds (own 16-ch slice, all 64 pts) ----
        // C/D layout: col = lane&15 (channel), row = (lane>>4)*4 + reg (point)
#pragma unroll
        for (int q = 0; q < 4; ++q)
#pragma unroll
            for (int r = 0; r < 4; ++r) {
                const int d = q * 16 + lg * 4 + r;
                const int byte = (d * 256 + ch * 2) ^ ((d & 7) << 4);
                const float fval = (float)*reinterpret_cast<const f16*>(
                    reinterpret_cast<const char*>(f_lds) + byte);
                const float hv = fmaxf(acc[q][r], 0.f) * fval;
                *reinterpret_cast<f16*>(reinterpret_cast<char*>(h_lds) + byte) = (f16)hv;
            }
        __syncthreads();  // bar2: h complete (and all os/f reads done)

        // ---- Layer 2: out = relu(h @ W2 + b2) ----------------------------
        f32x4 acc2[4];
#pragma unroll
        for (int q = 0; q < 4; ++q)
            acc2[q] = (f32x4){b2v, b2v, b2v, b2v};

#pragma unroll
        for (int s = 0; s < 4; ++s) {
            f16x8 af[4];
#pragma unroll
            for (int q = 0; q < 4; ++q) {
                const int p = q * 16 + l15;
                const int byte = (p * 256 + (s * 32 + lg * 8) * 2) ^ ((p & 7) << 4);
                U16 tmp;
                tmp.u = *reinterpret_cast<const uint4*>(reinterpret_cast<const char*>(h_lds) + byte);
                af[q] = tmp.h;
            }
#pragma unroll
            for (int q = 0; q < 4; ++q)
                acc2[q] = __builtin_amdgcn_mfma_f32_16x16x32_f16(af[q], w2f[s], acc2[q], 0, 0, 0);
        }

#pragma unroll
        for (int q = 0; q < 4; ++q)
#pragma unroll
            for (int r = 0; r < 4; ++r) {
                const int d = q * 16 + lg * 4 + r;
                const long long gp = base + d;
                if (gp < n)
                    out[gp * C + ch] = fmaxf(acc2[q][r], 0.f);
            }
        // No 3rd barrier: next stage writes os/f only; the live h_lds reads
        // belong to threads that must pass bar1(i+1) before h is rewritten.
    }
}

// -------------------------------------------------------------------------
// Launch
// -------------------------------------------------------------------------
extern "C" void kernel_launch(void* const* d_in, const int* in_sizes, int n_in,
                              void* d_out, int out_size, void* d_ws, size_t ws_size,
                              hipStream_t stream) {
    const float* feats = (const float*)d_in[0];
    const float* W1    = (const float*)d_in[1];
    const float* b1    = (const float*)d_in[2];
    const float* W2    = (const float*)d_in[3];
    const float* b2    = (const float*)d_in[4];
    const int*   idx   = (const int*)d_in[5];
    float*       out   = (float*)d_out;

    const int n = in_sizes[5];

    // Workspace: cnt[V] int | bucket[V*64] int | pooled[V*C] f16
    int* cnt    = (int*)d_ws;
    int* bucket = cnt + V;
    __half* pooled = (__half*)(bucket + (size_t)V * BKT);

    zero_cnt<<<V / (256 * 4), 256, 0, stream>>>((int4*)cnt);
    bucket_scatter<<<(n + 255) / 256, 256, 0, stream>>>(idx, cnt, bucket, n);
    pool_bucket<<<V / 4, 256, 0, stream>>>(feats, bucket, cnt, pooled);
    mlp_mfma<<<512, MLP_BLOCK, 0, stream>>>(feats, W1, b1, W2, b2, idx,
                                            pooled, out, n);
}